// Round 1
// baseline (453.157 us; speedup 1.0000x reference)
//
#include <hip/hip_runtime.h>
#include <hip/hip_bf16.h>

#define N 8192
#define D 128
#define TOPK 14
#define RPB 16      // rows per workgroup in main pass
#define CCH 128     // j-columns per chunk
#define NW 4        // waves per block (256 threads)
#define EPS 1e-10f

typedef short short8 __attribute__((ext_vector_type(8)));
typedef float floatx4 __attribute__((ext_vector_type(4)));

// ---------------- setup: fp32 -> bf16 copy of X, zero the accumulator ----------------
__global__ void k_convert(const float* __restrict__ x, __hip_bfloat16* __restrict__ xb,
                          float* __restrict__ acc) {
    int idx = blockIdx.x * blockDim.x + threadIdx.x;
    if (idx == 0) *acc = 0.f;
    if (idx < N * D) xb[idx] = __float2bfloat16(x[idx]);
}

// ---------------- setup: row squared norms (fp32) ----------------
__global__ void k_sqnorm(const float* __restrict__ x, float* __restrict__ sq) {
    int i = blockIdx.x * blockDim.x + threadIdx.x;
    if (i < N) {
        const float4* p = (const float4*)(x + i * D);
        float s = 0.f;
#pragma unroll
        for (int t = 0; t < D / 4; ++t) {
            float4 v = p[t];
            s += v.x * v.x + v.y * v.y + v.z * v.z + v.w * v.w;
        }
        sq[i] = s;
    }
}

// ---------------- main pass: base loss term over all pairs + per-row top-14 ----------------
// One WG owns RPB=16 rows, sweeps all 8192 columns in 128-col chunks.
// G tile via bf16 MFMA; A-fragments (the WG's rows) stay in registers all kernel.
__global__ void __launch_bounds__(256, 2)
k_main(const __hip_bfloat16* __restrict__ xb, const float* __restrict__ sq,
       const float2* __restrict__ lo, float* __restrict__ acc, int* __restrict__ nbr) {
    __shared__ float s_cand_d2[RPB][CCH];
    __shared__ int   s_cand_j[RPB][CCH];
    __shared__ float s_top_d2[RPB][TOPK];
    __shared__ int   s_top_j[RPB][TOPK];
    __shared__ float s_thr[RPB];
    __shared__ int   s_cnt[RPB];
    __shared__ int   s_nfill[RPB];
    __shared__ float2 s_lo[RPB];
    __shared__ float s_sq[RPB];
    __shared__ float s_wsum[NW];

    const int tid  = threadIdx.x;
    const int row0 = blockIdx.x * RPB;
    const int wave = tid >> 6;
    const int lane = tid & 63;
    const int col  = lane & 15;   // C/D col = lane&15 ; also A/B "m/n" index
    const int quad = lane >> 4;   // C/D row group ; A/B k-group

    if (tid < RPB) {
        s_thr[tid]   = INFINITY;
        s_cnt[tid]   = 0;
        s_nfill[tid] = 0;
        s_lo[tid]    = lo[row0 + tid];
        s_sq[tid]    = sq[row0 + tid];
    }
    __syncthreads();

    const short* xbs = (const short*)xb;

    // A fragments for this WG's 16 rows: A[m=lane&15][k=quad*8+t], k0 in {0,32,64,96}
    const int rowA = row0 + col;
    short8 afrag[4];
#pragma unroll
    for (int k = 0; k < 4; ++k)
        afrag[k] = *(const short8*)(xbs + rowA * D + k * 32 + quad * 8);

    float tsum = 0.f;

    for (int j0 = 0; j0 < N; j0 += CCH) {
        // each wave handles 2 of the 8 column tiles
#pragma unroll
        for (int ci = 0; ci < 2; ++ci) {
            const int ct   = wave * 2 + ci;
            const int jcol = j0 + ct * 16 + col;  // this lane's column (same for all 4 acc regs)
            floatx4 c = {0.f, 0.f, 0.f, 0.f};
#pragma unroll
            for (int k = 0; k < 4; ++k) {
                short8 b = *(const short8*)(xbs + jcol * D + k * 32 + quad * 8);
                c = __builtin_amdgcn_mfma_f32_16x16x32_bf16(afrag[k], b, c, 0, 0, 0);
            }
            const float  sqj = sq[jcol];
            const float2 loj = lo[jcol];
#pragma unroll
            for (int r = 0; r < 4; ++r) {
                const int lrow = quad * 4 + r;   // C/D row = (lane>>4)*4 + reg
                const int irow = row0 + lrow;
                float d2 = s_sq[lrow] + sqj - 2.f * c[r];
                d2 = (jcol == irow) ? 0.f : fmaxf(d2, 0.f);
                // base term: (1-hi_sim) * log(1-lo_sim+eps)   (==0 on diagonal since hi_sim==1)
                const float dhi   = sqrtf(d2);
                const float his   = __expf(-dhi);
                const float dx    = s_lo[lrow].x - loj.x;
                const float dy    = s_lo[lrow].y - loj.y;
                const float dlo   = sqrtf(dx * dx + dy * dy);
                const float losim = __fdividef(1.f, 1.f + dlo);
                tsum += (1.f - his) * __logf(1.f - losim + EPS);
                // top-k candidate push (rare after warm-up)
                if (d2 < s_thr[lrow]) {
                    int p = atomicAdd(&s_cnt[lrow], 1);
                    s_cand_d2[lrow][p] = d2;
                    s_cand_j[lrow][p]  = jcol;
                }
            }
        }
        __syncthreads();
        // serial insertion by one leader thread per row
        if (tid < RPB) {
            int   cnt = s_cnt[tid];
            int   nf  = s_nfill[tid];
            float thr = s_thr[tid];
            for (int c2 = 0; c2 < cnt; ++c2) {
                float d2v = s_cand_d2[tid][c2];
                int   jv  = s_cand_j[tid][c2];
                if (nf < TOPK) {
                    s_top_d2[tid][nf] = d2v;
                    s_top_j[tid][nf]  = jv;
                    ++nf;
                    if (nf == TOPK) {
                        float m = -1.f;
                        for (int t = 0; t < TOPK; ++t) m = fmaxf(m, s_top_d2[tid][t]);
                        thr = m;
                    }
                } else if (d2v < thr) {
                    int   mp = 0;
                    float mv = s_top_d2[tid][0];
                    for (int t = 1; t < TOPK; ++t) {
                        float v = s_top_d2[tid][t];
                        if (v > mv) { mv = v; mp = t; }
                    }
                    s_top_d2[tid][mp] = d2v;
                    s_top_j[tid][mp]  = jv;
                    float m = -1.f;
                    for (int t = 0; t < TOPK; ++t) m = fmaxf(m, s_top_d2[tid][t]);
                    thr = m;
                }
            }
            s_cnt[tid]   = 0;
            s_nfill[tid] = nf;
            s_thr[tid]   = thr;
        }
        __syncthreads();
    }

    // write neighbor lists
    if (tid < RPB) {
        for (int t = 0; t < TOPK; ++t) nbr[(row0 + tid) * TOPK + t] = s_top_j[tid][t];
    }

    // reduce the base-term partial sum
#pragma unroll
    for (int off = 32; off > 0; off >>= 1) tsum += __shfl_down(tsum, off);
    if (lane == 0) s_wsum[wave] = tsum;
    __syncthreads();
    if (tid == 0) atomicAdd(acc, s_wsum[0] + s_wsum[1] + s_wsum[2] + s_wsum[3]);
}

// ---------------- correction pass: swap base term -> adjacency term for top-k pairs ----------------
__global__ void k_corr(const float* __restrict__ x, const float* __restrict__ sq,
                       const float2* __restrict__ lo, const int* __restrict__ nbr,
                       float* __restrict__ acc) {
    const int tid    = threadIdx.x;
    const int lane   = tid & 63;
    const int wave   = tid >> 6;
    const int gw     = blockIdx.x * NW + wave;
    const int nwaves = gridDim.x * NW;
    float dsum = 0.f;
    for (int p = gw; p < N * TOPK; p += nwaves) {
        const int i = p / TOPK;
        const int j = nbr[p];
        float a0 = x[i * D + lane], a1 = x[i * D + 64 + lane];
        float b0 = x[j * D + lane], b1 = x[j * D + 64 + lane];
        float dot = a0 * b0 + a1 * b1;
#pragma unroll
        for (int off = 32; off > 0; off >>= 1) dot += __shfl_down(dot, off);
        if (lane == 0) {
            float d2 = sq[i] + sq[j] - 2.f * dot;
            d2 = (i == j) ? 0.f : fmaxf(d2, 0.f);
            float dhi = sqrtf(d2);
            float his = __expf(-dhi);
            float2 li = lo[i], lj = lo[j];
            float dx = li.x - lj.x, dy = li.y - lj.y;
            float dlo = sqrtf(dx * dx + dy * dy);
            float losim = __fdividef(1.f, 1.f + dlo);
            dsum += his * __logf(losim + EPS) - (1.f - his) * __logf(1.f - losim + EPS);
        }
    }
    __shared__ float s[NW];
    if (lane == 0) s[wave] = dsum;
    __syncthreads();
    if (tid == 0) atomicAdd(acc, s[0] + s[1] + s[2] + s[3]);
}

// ---------------- finalize ----------------
__global__ void k_final(const float* __restrict__ acc, float* __restrict__ out) {
    out[0] = acc[0] * (-100.f / ((float)N * (float)N));
}

extern "C" void kernel_launch(void* const* d_in, const int* in_sizes, int n_in,
                              void* d_out, int out_size, void* d_ws, size_t ws_size,
                              hipStream_t stream) {
    const float*  x  = (const float*)d_in[0];
    const float2* lo = (const float2*)d_in[1];
    float*        out = (float*)d_out;

    char* ws = (char*)d_ws;
    float*          acc = (float*)ws;                       // 1 float
    float*          sq  = (float*)(ws + 256);               // 8192 floats -> ends 33024
    __hip_bfloat16* xb  = (__hip_bfloat16*)(ws + 33280);    // 2 MiB      -> ends 2130432
    int*            nbr = (int*)(ws + 33280 + 2 * 1024 * 1024); // 8192*14 ints

    k_convert<<<dim3((N * D + 255) / 256), dim3(256), 0, stream>>>(x, xb, acc);
    k_sqnorm<<<dim3(N / 256), dim3(256), 0, stream>>>(x, sq);
    k_main<<<dim3(N / RPB), dim3(256), 0, stream>>>(xb, sq, lo, acc, nbr);
    k_corr<<<dim3(512), dim3(256), 0, stream>>>(x, sq, lo, nbr, acc);
    k_final<<<dim3(1), dim3(1), 0, stream>>>(acc, out);
}